// Round 3
// baseline (846.735 us; speedup 1.0000x reference)
//
#include <hip/hip_runtime.h>
#include <hip/hip_fp16.h>

#define NNODES   4000
#define TSTEPS   32
#define HDIM     64
#define ECOUNT   1024000
#define NTOT     128000        // NNODES * TSTEPS
#define BATCHB   8
#define NNEUR    500
#define TEBD     16
#define NSTEPS   12

// packed u32 histogram cell: count in [31:23] (<=511), sum(w) fixed-point
// 2^-18 in [22:0] (max 32.0, needs 5 int bits; deg err <= ~2e-5, harmless)
#define CNT_SHIFT 23
#define SUM_MASK  0x7FFFFFu
#define SUM_SCALE 262144.0f    // 2^18
#define SLOTS     32           // fixed bucket stride; P(indeg>32) ~ 1e-10 (Poisson mean 8)
#define REC_BLOCKS (NNODES / 16)   // 250
#define HIST_BLOCKS (ECOUNT / 512) // 2000: 2 edges per thread

#define ROWS_PER_WAVE  5       // gather: rows per wave; 20 rows/block, 20 | 500
#define ROWS_PER_BLOCK 20
#define GATHER_BLOCKS  (NTOT / ROWS_PER_BLOCK)   // 6400

typedef _Float16 half8_t __attribute__((ext_vector_type(8)));
typedef float    f32x4_t __attribute__((ext_vector_type(4)));

__device__ __forceinline__ float sigmoidf_(float x) {
    return 1.0f / (1.0f + __expf(-x));
}
__device__ __forceinline__ float tanhf_(float x) {
    return 1.0f - 2.0f / (1.0f + __expf(2.0f * x));
}

// ---------------- fused: MFMA GRU recurrence (blocks 0..249) +
//                  packed degree/count histogram (blocks 250..2249) --------
// Histogram: one u32 atomic per edge packs sum(w) fixed-point + count; the
// returned old value's count IS the edge's rank in its dst bucket -> direct
// write se32[d*SLOTS+rank]. se32 entry is 4 B: (s:17 | w:15 fixed-point
// 2^-15, err<=1.5e-5 << fp16 xwh quantization). With 4 B entries ranks 0-15
// share ONE 64B line -> tests whether scattered-store line merging exists
// (round-2 showed WRITE_SIZE is line-granular: 1M x 64B = the 65 MB pole).
// 2 edges/thread: two independent load->atomic->store chains for ILP.
// Recurrence: one block (4 waves) owns 16 nodes for all 32 timesteps; wave
// wv owns the 16-feature stripe of each gate. Weight B-frags in VGPRs; LDS
// only a 2x(16x72) fp16 ping-pong for the C->A h transpose; 1 barrier/step.
// Fragment layouts (gfx950 16x16x32): A[m=lane&15][k=quad*8+j],
// B[k=quad*8+j][n=lane&15], C[m=quad*4+reg][n=lane&15].
__global__ __launch_bounds__(256) void k_recHist(
    const float* __restrict__ x, const float* __restrict__ Wih,
    const float* __restrict__ Whh, const float* __restrict__ bih,
    const float* __restrict__ bhh, const float* __restrict__ Wg,
    _Float16* __restrict__ xwh,
    const int* __restrict__ ei, const float* __restrict__ ea,
    unsigned* __restrict__ dc, unsigned* __restrict__ se32)
{
    __shared__ __align__(16) _Float16 hbuf[2][16 * 72];   // stride 72: conflict-free

    const int tid = threadIdx.x;

    if (blockIdx.x >= REC_BLOCKS) {
        // -------- histogram path: 2 edges per thread --------
        int e0 = (blockIdx.x - REC_BLOCKS) * 512 + tid;
        int e1 = e0 + 256;
        int s0 = ei[e0],          s1 = ei[e1];
        int d0 = ei[ECOUNT + e0], d1 = ei[ECOUNT + e1];
        float w0 = ea[e0],        w1 = ea[e1];
        unsigned q0 = (unsigned)(w0 * 32768.0f + 0.5f); q0 = q0 > 32767u ? 32767u : q0;
        unsigned q1 = (unsigned)(w1 * 32768.0f + 0.5f); q1 = q1 > 32767u ? 32767u : q1;
        unsigned fx0 = (unsigned)(w0 * SUM_SCALE + 0.5f);
        unsigned fx1 = (unsigned)(w1 * SUM_SCALE + 0.5f);
        unsigned old0 = atomicAdd(&dc[d0], (1u << CNT_SHIFT) | fx0);
        unsigned old1 = atomicAdd(&dc[d1], (1u << CNT_SHIFT) | fx1);
        int r0 = (int)(old0 >> CNT_SHIFT);
        int r1 = (int)(old1 >> CNT_SHIFT);
        if (r0 < SLOTS) se32[d0 * SLOTS + r0] = ((unsigned)s0 << 15) | q0;
        if (r1 < SLOTS) se32[d1 * SLOTS + r1] = ((unsigned)s1 << 15) | q1;
        return;
    }

    // -------- recurrence path --------
    const int lane = tid & 63;
    const int wv   = tid >> 6;       // feature tile 0..3
    const int c    = lane & 15;
    const int quad = lane >> 4;
    const int n0   = blockIdx.x * 16;

    auto makeB = [&](const float* W, int row, int k0) -> half8_t {
        const float4* p = (const float4*)(W + (size_t)row * HDIM + k0);
        float4 u = p[0], v = p[1];
        half8_t h;
        h[0] = (_Float16)u.x; h[1] = (_Float16)u.y; h[2] = (_Float16)u.z; h[3] = (_Float16)u.w;
        h[4] = (_Float16)v.x; h[5] = (_Float16)v.y; h[6] = (_Float16)v.z; h[7] = (_Float16)v.w;
        return h;
    };

    half8_t Bxr[2], Bxz[2], Bxn[2], Bhr[2], Bhz[2], Bhn[2], Bw[2];
#pragma unroll
    for (int kt = 0; kt < 2; ++kt) {
        int k0 = kt * 32 + quad * 8;
        Bxr[kt] = makeB(Wih, wv * 16 + c, k0);
        Bxz[kt] = makeB(Wih, 64 + wv * 16 + c, k0);
        Bxn[kt] = makeB(Wih, 128 + wv * 16 + c, k0);
        Bhr[kt] = makeB(Whh, wv * 16 + c, k0);
        Bhz[kt] = makeB(Whh, 64 + wv * 16 + c, k0);
        Bhn[kt] = makeB(Whh, 128 + wv * 16 + c, k0);
        Bw[kt]  = makeB(Wg, wv * 16 + c, k0);
    }

    const int f = wv * 16 + c;
    const float brz_r = bih[f] + bhh[f];
    const float brz_z = bih[64 + f] + bhh[64 + f];
    const float bin_  = bih[128 + f];
    const float bhn_  = bhh[128 + f];

    float hreg[4] = {0.f, 0.f, 0.f, 0.f};
    half8_t ah[2];

    const float* xp = x + (size_t)(n0 + c) * (TSTEPS * HDIM) + quad * 8;

    float4 xq0[4], xq1[4];
    {
        const float* p0 = xp;
        xq0[0] = *(const float4*)(p0);      xq0[1] = *(const float4*)(p0 + 4);
        xq0[2] = *(const float4*)(p0 + 32); xq0[3] = *(const float4*)(p0 + 36);
        const float* p1 = xp + HDIM;
        xq1[0] = *(const float4*)(p1);      xq1[1] = *(const float4*)(p1 + 4);
        xq1[2] = *(const float4*)(p1 + 32); xq1[3] = *(const float4*)(p1 + 36);
    }

    auto step = [&](int t, float4* xq) {
        half8_t ax[2];
#pragma unroll
        for (int kt = 0; kt < 2; ++kt) {
            float4 u = xq[kt * 2], v = xq[kt * 2 + 1];
            half8_t a;
            a[0] = (_Float16)u.x; a[1] = (_Float16)u.y; a[2] = (_Float16)u.z; a[3] = (_Float16)u.w;
            a[4] = (_Float16)v.x; a[5] = (_Float16)v.y; a[6] = (_Float16)v.z; a[7] = (_Float16)v.w;
            ax[kt] = a;
        }
        if (t + 2 < TSTEPS) {
            const float* pt = xp + (size_t)(t + 2) * HDIM;
            xq[0] = *(const float4*)(pt);      xq[1] = *(const float4*)(pt + 4);
            xq[2] = *(const float4*)(pt + 32); xq[3] = *(const float4*)(pt + 36);
        }

        f32x4_t Cr  = (f32x4_t){0.f, 0.f, 0.f, 0.f};
        f32x4_t Cz  = (f32x4_t){0.f, 0.f, 0.f, 0.f};
        f32x4_t Cnx = (f32x4_t){0.f, 0.f, 0.f, 0.f};
        f32x4_t Cnh = (f32x4_t){0.f, 0.f, 0.f, 0.f};

#pragma unroll
        for (int kt = 0; kt < 2; ++kt) {
            Cr  = __builtin_amdgcn_mfma_f32_16x16x32_f16(ax[kt], Bxr[kt], Cr, 0, 0, 0);
            Cz  = __builtin_amdgcn_mfma_f32_16x16x32_f16(ax[kt], Bxz[kt], Cz, 0, 0, 0);
            Cnx = __builtin_amdgcn_mfma_f32_16x16x32_f16(ax[kt], Bxn[kt], Cnx, 0, 0, 0);
        }
        if (t > 0) {
#pragma unroll
            for (int kt = 0; kt < 2; ++kt) {
                Cr  = __builtin_amdgcn_mfma_f32_16x16x32_f16(ah[kt], Bhr[kt], Cr, 0, 0, 0);
                Cz  = __builtin_amdgcn_mfma_f32_16x16x32_f16(ah[kt], Bhz[kt], Cz, 0, 0, 0);
                Cnh = __builtin_amdgcn_mfma_f32_16x16x32_f16(ah[kt], Bhn[kt], Cnh, 0, 0, 0);
            }
        }

        _Float16* hb = hbuf[t & 1];
#pragma unroll
        for (int r = 0; r < 4; ++r) {
            float rr = sigmoidf_(Cr[r] + brz_r);
            float zz = sigmoidf_(Cz[r] + brz_z);
            float nn = tanhf_(Cnx[r] + bin_ + rr * (Cnh[r] + bhn_));
            float hn = (1.0f - zz) * nn + zz * hreg[r];
            hreg[r] = hn;
            hb[(quad * 4 + r) * 72 + f] = (_Float16)hn;
        }

        __syncthreads();

#pragma unroll
        for (int kt = 0; kt < 2; ++kt)
            ah[kt] = *(half8_t*)&hb[c * 72 + kt * 32 + quad * 8];

        f32x4_t Cw = (f32x4_t){0.f, 0.f, 0.f, 0.f};
#pragma unroll
        for (int kt = 0; kt < 2; ++kt)
            Cw = __builtin_amdgcn_mfma_f32_16x16x32_f16(ah[kt], Bw[kt], Cw, 0, 0, 0);

#pragma unroll
        for (int r = 0; r < 4; ++r) {
            int row = (n0 + quad * 4 + r) * TSTEPS + t;
            xwh[(size_t)row * HDIM + f] = (_Float16)Cw[r];
        }
    };

#pragma unroll 1
    for (int tt = 0; tt < TSTEPS; tt += 2) {
        step(tt, xq0);
        step(tt + 1, xq1);
    }
}

// ---------------- bucket gather fused with per-(b,t) reduction + final head
// Each wave owns ROWS_PER_WAVE=5 consecutive dst rows (block: 20 rows; 20|500
// so a block never straddles a bt bucket). One accumulator per wave across
// its rows -> 64 S-atomics per block (25-way collisions). Buckets are read
// as uint4 (4 packed edges / 16B load). dis recomputed from L2-resident dc.
// The LAST block to finish (done-counter) runs the attention/FC head inline;
// it must read S with agent-scope atomic loads (per-XCD L2s are not
// coherent and there is no kernel-boundary acquire between the S atomics
// and the read here).
__global__ __launch_bounds__(256) void k_gatherFinal(
    const _Float16* __restrict__ xwh, const unsigned* __restrict__ dc,
    const unsigned* __restrict__ se32, float* __restrict__ S,
    unsigned* __restrict__ fin,
    const float* __restrict__ W1, const float* __restrict__ W2,
    const float* __restrict__ fcW, const float* __restrict__ fcb,
    float* __restrict__ out)
{
    const int tid  = threadIdx.x;
    const int lane = tid & 63;
    const int wv   = tid >> 6;
    const int d0   = blockIdx.x * ROWS_PER_BLOCK + wv * ROWS_PER_WAVE;

    // hoist independent per-row scalars: packed histogram + self-loop value
    unsigned pk[ROWS_PER_WAVE];
    float    sf[ROWS_PER_WAVE];
#pragma unroll
    for (int i = 0; i < ROWS_PER_WAVE; ++i) pk[i] = dc[d0 + i];
#pragma unroll
    for (int i = 0; i < ROWS_PER_WAVE; ++i)
        sf[i] = (float)xwh[(size_t)(d0 + i) * HDIM + lane];

    float acc = 0.f;
#pragma unroll
    for (int i = 0; i < ROWS_PER_WAVE; ++i) {
        const int d = d0 + i;
        const float dd = rsqrtf(1.0f + (float)(pk[i] & SUM_MASK) * 0x1p-18f);
        int cnt = (int)(pk[i] >> CNT_SHIFT);
        cnt = cnt < SLOTS ? cnt : SLOTS;
        const unsigned* bkt = se32 + (size_t)d * SLOTS;

        float a0 = dd * sf[i];   // self-loop (dis[d]*xw), outer dd applied below
        float a1 = 0.f, a2 = 0.f, a3 = 0.f;
        int j = 0;
        for (; j + 4 <= cnt; j += 4) {
            uint4 q = *(const uint4*)(bkt + j);
            int s0 = (int)(q.x >> 15), s1 = (int)(q.y >> 15);
            int s2 = (int)(q.z >> 15), s3 = (int)(q.w >> 15);
            unsigned p0 = dc[s0], p1 = dc[s1], p2 = dc[s2], p3 = dc[s3];
            float c0 = rsqrtf(1.0f + (float)(p0 & SUM_MASK) * 0x1p-18f) * ((float)(q.x & 0x7FFFu) * 0x1p-15f);
            float c1 = rsqrtf(1.0f + (float)(p1 & SUM_MASK) * 0x1p-18f) * ((float)(q.y & 0x7FFFu) * 0x1p-15f);
            float c2 = rsqrtf(1.0f + (float)(p2 & SUM_MASK) * 0x1p-18f) * ((float)(q.z & 0x7FFFu) * 0x1p-15f);
            float c3 = rsqrtf(1.0f + (float)(p3 & SUM_MASK) * 0x1p-18f) * ((float)(q.w & 0x7FFFu) * 0x1p-15f);
            float v0 = (float)xwh[(size_t)s0 * HDIM + lane];
            float v1 = (float)xwh[(size_t)s1 * HDIM + lane];
            float v2 = (float)xwh[(size_t)s2 * HDIM + lane];
            float v3 = (float)xwh[(size_t)s3 * HDIM + lane];
            a0 = fmaf(c0, v0, a0);
            a1 = fmaf(c1, v1, a1);
            a2 = fmaf(c2, v2, a2);
            a3 = fmaf(c3, v3, a3);
        }
        for (; j < cnt; ++j) {
            unsigned u = bkt[j];
            int s = (int)(u >> 15);
            unsigned pe = dc[s];
            a0 = fmaf(rsqrtf(1.0f + (float)(pe & SUM_MASK) * 0x1p-18f) * ((float)(u & 0x7FFFu) * 0x1p-15f),
                      (float)xwh[(size_t)s * HDIM + lane], a0);
        }
        acc = fmaf(dd, (a0 + a1) + (a2 + a3), acc);
    }

    __shared__ float red[256];
    red[tid] = acc;
    __syncthreads();
    if (tid < 64) {
        float s = red[tid] + red[64 + tid] + red[128 + tid] + red[192 + tid];
        atomicAdd(&S[((blockIdx.x * ROWS_PER_BLOCK) / NNEUR) * HDIM + tid], s);  // bt = d/500
    }

    // ---- last-block-done: run the attention MLP + pooling + FC head ----
    __threadfence();                 // S-atomics visible before counter bump
    __shared__ int lastFlag;
    __syncthreads();
    if (tid == 0) {
        unsigned prev = atomicAdd(fin, 1u);
        lastFlag = (prev == GATHER_BLOCKS - 1);
    }
    __syncthreads();
    if (!lastFlag) return;

    auto ldS = [&](int i) -> float {
        return __hip_atomic_load(&S[i], __ATOMIC_RELAXED, __HIP_MEMORY_SCOPE_AGENT);
    };

    __shared__ float xt[256];
    __shared__ float a1s[128];
    __shared__ float attn[256];
    __shared__ float pooled[512];

    {
        float s = 0.f;
#pragma unroll
        for (int hh = 0; hh < 64; ++hh) s += ldS(tid * 64 + hh);
        xt[tid] = s * (1.0f / 32000.0f);
    }
    __syncthreads();
    if (tid < 128) {
        int b = tid >> 4, i = tid & 15;
        float s = 0.f;
#pragma unroll
        for (int t = 0; t < 32; ++t) s += xt[b * 32 + t] * W1[i * 32 + t];
        a1s[tid] = fmaxf(s, 0.f);
    }
    __syncthreads();
    {
        int b = tid >> 5, t = tid & 31;
        float s = 0.f;
#pragma unroll
        for (int i = 0; i < 16; ++i) s += a1s[b * 16 + i] * W2[t * 16 + i];
        attn[tid] = 1.0f / (1.0f + __expf(-s));
    }
    __syncthreads();
    for (int o = tid; o < 512; o += 256) {
        int b = o >> 6, h = o & 63;
        float s = 0.f;
#pragma unroll
        for (int t = 0; t < 32; ++t) s += attn[b * 32 + t] * ldS((b * 32 + t) * 64 + h);
        pooled[o] = s;
    }
    __syncthreads();
    if (tid < BATCHB * NSTEPS) {
        int b = tid / NSTEPS, st = tid % NSTEPS;
        float acc2 = fcb[st];
#pragma unroll
        for (int h = 0; h < 64; ++h) acc2 += pooled[b * 64 + h] * fcW[st * 64 + h];
        out[b * NSTEPS + st] = acc2;
    }
}

extern "C" void kernel_launch(void* const* d_in, const int* in_sizes, int n_in,
                              void* d_out, int out_size, void* d_ws, size_t ws_size,
                              hipStream_t stream) {
    const float* x   = (const float*)d_in[0];
    const int*   ei  = (const int*)  d_in[1];
    const float* ea  = (const float*)d_in[2];
    // d_in[3] = batch: unused by the reference computation
    const float* Wih = (const float*)d_in[4];
    const float* Whh = (const float*)d_in[5];
    const float* bih = (const float*)d_in[6];
    const float* bhh = (const float*)d_in[7];
    const float* Wg  = (const float*)d_in[8];
    const float* W1  = (const float*)d_in[9];
    const float* W2  = (const float*)d_in[10];
    const float* fcW = (const float*)d_in[11];
    const float* fcb = (const float*)d_in[12];
    float* out = (float*)d_out;

    // workspace layout (~33.5 MB); dc, S, fin adjacent -> one memset clears all
    char* p = (char*)d_ws;
    unsigned* dc = (unsigned*)p;   p += sizeof(unsigned) * NTOT;                                    // 512000 B
    float* S = (float*)p;          p += sizeof(float) * 256 * HDIM;                                 // 65536 B
    unsigned* fin = (unsigned*)p;  p += 16;                                                         // pad to 16B
    unsigned* se32 = (unsigned*)p; p += sizeof(unsigned) * (size_t)NTOT * SLOTS;                    // 16.38 MB
    _Float16* xwh = (_Float16*)p;  p += sizeof(_Float16) * (size_t)NTOT * HDIM;                     // 16.38 MB

    hipMemsetAsync(dc, 0, sizeof(unsigned) * NTOT + sizeof(float) * 256 * HDIM + 16, stream);
    k_recHist <<<REC_BLOCKS + HIST_BLOCKS, 256, 0, stream>>>(
        x, Wih, Whh, bih, bhh, Wg, xwh, ei, ea, dc, se32);
    k_gatherFinal <<<GATHER_BLOCKS, 256, 0, stream>>>(
        xwh, dc, se32, S, fin, W1, W2, fcW, fcb, out);
}

// Round 4
// 246.674 us; speedup vs baseline: 3.4326x; 3.4326x over previous
//
#include <hip/hip_runtime.h>
#include <hip/hip_fp16.h>

#define NNODES   4000
#define TSTEPS   32
#define HDIM     64
#define ECOUNT   1024000
#define NTOT     128000        // NNODES * TSTEPS
#define BATCHB   8
#define NNEUR    500
#define TEBD     16
#define NSTEPS   12

// packed u32 histogram cell: count in [31:23] (<=511), sum(w) fixed-point
// 2^-18 in [22:0] (max 32.0, needs 5 int bits; deg err <= ~2e-5, harmless)
#define CNT_SHIFT 23
#define SUM_MASK  0x7FFFFFu
#define SUM_SCALE 262144.0f    // 2^18
#define SLOTS     32           // fixed bucket stride; P(indeg>32) ~ 1e-10 (Poisson mean 8)
#define REC_BLOCKS (NNODES / 16)   // 250
#define HIST_BLOCKS (ECOUNT / 512) // 2000: 2 edges per thread

#define ROWS_PER_WAVE  5       // gather: rows per wave; 20 rows/block, 20 | 500
#define ROWS_PER_BLOCK 20
#define GATHER_BLOCKS  (NTOT / ROWS_PER_BLOCK)   // 6400

typedef _Float16 half8_t __attribute__((ext_vector_type(8)));
typedef float    f32x4_t __attribute__((ext_vector_type(4)));

__device__ __forceinline__ float sigmoidf_(float x) {
    return 1.0f / (1.0f + __expf(-x));
}
__device__ __forceinline__ float tanhf_(float x) {
    return 1.0f - 2.0f / (1.0f + __expf(2.0f * x));
}

// ---------------- fused: MFMA GRU recurrence (blocks 0..249) +
//                  packed degree/count histogram (blocks 250..2249) --------
// Histogram: one u32 atomic per edge packs sum(w) fixed-point + count; the
// returned old value's count IS the edge's rank in its dst bucket -> direct
// write se32[d*SLOTS+rank]. se32 entry is 4 B: (s:17 | w:15 fixed-point
// 2^-15, err<=1.5e-5 << fp16 xwh quantization). Ranks 0-15 of a bucket
// share ONE 64B line -> WRITE_SIZE diagnostic for scattered-store merging
// (round-2: WRITE_SIZE is line-granular, 1M x 64B was the ~65 MB pole).
// 2 edges/thread: two independent load->atomic->store chains for ILP.
// NOTE (round-3 lesson): do NOT put __threadfence() in a hot per-block
// path — agent-scope fences emit buffer_inv (L2 invalidate); 6400 of them
// destroyed dc/se32/xwh residency and made the gather latency-bound at
// 190 GB/s. Kernel boundaries provide the producer->consumer ordering.
__global__ __launch_bounds__(256) void k_recHist(
    const float* __restrict__ x, const float* __restrict__ Wih,
    const float* __restrict__ Whh, const float* __restrict__ bih,
    const float* __restrict__ bhh, const float* __restrict__ Wg,
    _Float16* __restrict__ xwh,
    const int* __restrict__ ei, const float* __restrict__ ea,
    unsigned* __restrict__ dc, unsigned* __restrict__ se32)
{
    __shared__ __align__(16) _Float16 hbuf[2][16 * 72];   // stride 72: conflict-free

    const int tid = threadIdx.x;

    if (blockIdx.x >= REC_BLOCKS) {
        // -------- histogram path: 2 edges per thread --------
        int e0 = (blockIdx.x - REC_BLOCKS) * 512 + tid;
        int e1 = e0 + 256;
        int s0 = ei[e0],          s1 = ei[e1];
        int d0 = ei[ECOUNT + e0], d1 = ei[ECOUNT + e1];
        float w0 = ea[e0],        w1 = ea[e1];
        unsigned q0 = (unsigned)(w0 * 32768.0f + 0.5f); q0 = q0 > 32767u ? 32767u : q0;
        unsigned q1 = (unsigned)(w1 * 32768.0f + 0.5f); q1 = q1 > 32767u ? 32767u : q1;
        unsigned fx0 = (unsigned)(w0 * SUM_SCALE + 0.5f);
        unsigned fx1 = (unsigned)(w1 * SUM_SCALE + 0.5f);
        unsigned old0 = atomicAdd(&dc[d0], (1u << CNT_SHIFT) | fx0);
        unsigned old1 = atomicAdd(&dc[d1], (1u << CNT_SHIFT) | fx1);
        int r0 = (int)(old0 >> CNT_SHIFT);
        int r1 = (int)(old1 >> CNT_SHIFT);
        if (r0 < SLOTS) se32[d0 * SLOTS + r0] = ((unsigned)s0 << 15) | q0;
        if (r1 < SLOTS) se32[d1 * SLOTS + r1] = ((unsigned)s1 << 15) | q1;
        return;
    }

    // -------- recurrence path --------
    const int lane = tid & 63;
    const int wv   = tid >> 6;       // feature tile 0..3
    const int c    = lane & 15;
    const int quad = lane >> 4;
    const int n0   = blockIdx.x * 16;

    auto makeB = [&](const float* W, int row, int k0) -> half8_t {
        const float4* p = (const float4*)(W + (size_t)row * HDIM + k0);
        float4 u = p[0], v = p[1];
        half8_t h;
        h[0] = (_Float16)u.x; h[1] = (_Float16)u.y; h[2] = (_Float16)u.z; h[3] = (_Float16)u.w;
        h[4] = (_Float16)v.x; h[5] = (_Float16)v.y; h[6] = (_Float16)v.z; h[7] = (_Float16)v.w;
        return h;
    };

    half8_t Bxr[2], Bxz[2], Bxn[2], Bhr[2], Bhz[2], Bhn[2], Bw[2];
#pragma unroll
    for (int kt = 0; kt < 2; ++kt) {
        int k0 = kt * 32 + quad * 8;
        Bxr[kt] = makeB(Wih, wv * 16 + c, k0);
        Bxz[kt] = makeB(Wih, 64 + wv * 16 + c, k0);
        Bxn[kt] = makeB(Wih, 128 + wv * 16 + c, k0);
        Bhr[kt] = makeB(Whh, wv * 16 + c, k0);
        Bhz[kt] = makeB(Whh, 64 + wv * 16 + c, k0);
        Bhn[kt] = makeB(Whh, 128 + wv * 16 + c, k0);
        Bw[kt]  = makeB(Wg, wv * 16 + c, k0);
    }

    const int f = wv * 16 + c;
    const float brz_r = bih[f] + bhh[f];
    const float brz_z = bih[64 + f] + bhh[64 + f];
    const float bin_  = bih[128 + f];
    const float bhn_  = bhh[128 + f];

    float hreg[4] = {0.f, 0.f, 0.f, 0.f};
    half8_t ah[2];

    const float* xp = x + (size_t)(n0 + c) * (TSTEPS * HDIM) + quad * 8;

    float4 xq0[4], xq1[4];
    {
        const float* p0 = xp;
        xq0[0] = *(const float4*)(p0);      xq0[1] = *(const float4*)(p0 + 4);
        xq0[2] = *(const float4*)(p0 + 32); xq0[3] = *(const float4*)(p0 + 36);
        const float* p1 = xp + HDIM;
        xq1[0] = *(const float4*)(p1);      xq1[1] = *(const float4*)(p1 + 4);
        xq1[2] = *(const float4*)(p1 + 32); xq1[3] = *(const float4*)(p1 + 36);
    }

    auto step = [&](int t, float4* xq) {
        half8_t ax[2];
#pragma unroll
        for (int kt = 0; kt < 2; ++kt) {
            float4 u = xq[kt * 2], v = xq[kt * 2 + 1];
            half8_t a;
            a[0] = (_Float16)u.x; a[1] = (_Float16)u.y; a[2] = (_Float16)u.z; a[3] = (_Float16)u.w;
            a[4] = (_Float16)v.x; a[5] = (_Float16)v.y; a[6] = (_Float16)v.z; a[7] = (_Float16)v.w;
            ax[kt] = a;
        }
        if (t + 2 < TSTEPS) {
            const float* pt = xp + (size_t)(t + 2) * HDIM;
            xq[0] = *(const float4*)(pt);      xq[1] = *(const float4*)(pt + 4);
            xq[2] = *(const float4*)(pt + 32); xq[3] = *(const float4*)(pt + 36);
        }

        f32x4_t Cr  = (f32x4_t){0.f, 0.f, 0.f, 0.f};
        f32x4_t Cz  = (f32x4_t){0.f, 0.f, 0.f, 0.f};
        f32x4_t Cnx = (f32x4_t){0.f, 0.f, 0.f, 0.f};
        f32x4_t Cnh = (f32x4_t){0.f, 0.f, 0.f, 0.f};

#pragma unroll
        for (int kt = 0; kt < 2; ++kt) {
            Cr  = __builtin_amdgcn_mfma_f32_16x16x32_f16(ax[kt], Bxr[kt], Cr, 0, 0, 0);
            Cz  = __builtin_amdgcn_mfma_f32_16x16x32_f16(ax[kt], Bxz[kt], Cz, 0, 0, 0);
            Cnx = __builtin_amdgcn_mfma_f32_16x16x32_f16(ax[kt], Bxn[kt], Cnx, 0, 0, 0);
        }
        if (t > 0) {
#pragma unroll
            for (int kt = 0; kt < 2; ++kt) {
                Cr  = __builtin_amdgcn_mfma_f32_16x16x32_f16(ah[kt], Bhr[kt], Cr, 0, 0, 0);
                Cz  = __builtin_amdgcn_mfma_f32_16x16x32_f16(ah[kt], Bhz[kt], Cz, 0, 0, 0);
                Cnh = __builtin_amdgcn_mfma_f32_16x16x32_f16(ah[kt], Bhn[kt], Cnh, 0, 0, 0);
            }
        }

        _Float16* hb = hbuf[t & 1];
#pragma unroll
        for (int r = 0; r < 4; ++r) {
            float rr = sigmoidf_(Cr[r] + brz_r);
            float zz = sigmoidf_(Cz[r] + brz_z);
            float nn = tanhf_(Cnx[r] + bin_ + rr * (Cnh[r] + bhn_));
            float hn = (1.0f - zz) * nn + zz * hreg[r];
            hreg[r] = hn;
            hb[(quad * 4 + r) * 72 + f] = (_Float16)hn;
        }

        __syncthreads();

#pragma unroll
        for (int kt = 0; kt < 2; ++kt)
            ah[kt] = *(half8_t*)&hb[c * 72 + kt * 32 + quad * 8];

        f32x4_t Cw = (f32x4_t){0.f, 0.f, 0.f, 0.f};
#pragma unroll
        for (int kt = 0; kt < 2; ++kt)
            Cw = __builtin_amdgcn_mfma_f32_16x16x32_f16(ah[kt], Bw[kt], Cw, 0, 0, 0);

#pragma unroll
        for (int r = 0; r < 4; ++r) {
            int row = (n0 + quad * 4 + r) * TSTEPS + t;
            xwh[(size_t)row * HDIM + f] = (_Float16)Cw[r];
        }
    };

#pragma unroll 1
    for (int tt = 0; tt < TSTEPS; tt += 2) {
        step(tt, xq0);
        step(tt + 1, xq1);
    }
}

// ---------------- bucket gather fused with per-(b,t) reduction ------------
// Each wave owns ROWS_PER_WAVE=5 consecutive dst rows (block: 20 rows; 20|500
// so a block never straddles a bt bucket). One accumulator per wave across
// its rows -> 64 S-atomics per block (25-way collisions). Buckets are read
// as uint4 (4 packed 4B edges / 16B load). dis recomputed from L2-resident
// dc; per-node GCN output y never materialized. No fences here (round-3).
__global__ __launch_bounds__(256) void k_gather(
    const _Float16* __restrict__ xwh, const unsigned* __restrict__ dc,
    const unsigned* __restrict__ se32, float* __restrict__ S)
{
    const int tid  = threadIdx.x;
    const int lane = tid & 63;
    const int wv   = tid >> 6;
    const int d0   = blockIdx.x * ROWS_PER_BLOCK + wv * ROWS_PER_WAVE;

    // hoist independent per-row scalars: packed histogram + self-loop value
    unsigned pk[ROWS_PER_WAVE];
    float    sf[ROWS_PER_WAVE];
#pragma unroll
    for (int i = 0; i < ROWS_PER_WAVE; ++i) pk[i] = dc[d0 + i];
#pragma unroll
    for (int i = 0; i < ROWS_PER_WAVE; ++i)
        sf[i] = (float)xwh[(size_t)(d0 + i) * HDIM + lane];

    float acc = 0.f;
#pragma unroll
    for (int i = 0; i < ROWS_PER_WAVE; ++i) {
        const int d = d0 + i;
        const float dd = rsqrtf(1.0f + (float)(pk[i] & SUM_MASK) * 0x1p-18f);
        int cnt = (int)(pk[i] >> CNT_SHIFT);
        cnt = cnt < SLOTS ? cnt : SLOTS;
        const unsigned* bkt = se32 + (size_t)d * SLOTS;

        float a0 = dd * sf[i];   // self-loop (dis[d]*xw), outer dd applied below
        float a1 = 0.f, a2 = 0.f, a3 = 0.f;
        int j = 0;
        for (; j + 4 <= cnt; j += 4) {
            uint4 q = *(const uint4*)(bkt + j);
            int s0 = (int)(q.x >> 15), s1 = (int)(q.y >> 15);
            int s2 = (int)(q.z >> 15), s3 = (int)(q.w >> 15);
            unsigned p0 = dc[s0], p1 = dc[s1], p2 = dc[s2], p3 = dc[s3];
            float c0 = rsqrtf(1.0f + (float)(p0 & SUM_MASK) * 0x1p-18f) * ((float)(q.x & 0x7FFFu) * 0x1p-15f);
            float c1 = rsqrtf(1.0f + (float)(p1 & SUM_MASK) * 0x1p-18f) * ((float)(q.y & 0x7FFFu) * 0x1p-15f);
            float c2 = rsqrtf(1.0f + (float)(p2 & SUM_MASK) * 0x1p-18f) * ((float)(q.z & 0x7FFFu) * 0x1p-15f);
            float c3 = rsqrtf(1.0f + (float)(p3 & SUM_MASK) * 0x1p-18f) * ((float)(q.w & 0x7FFFu) * 0x1p-15f);
            float v0 = (float)xwh[(size_t)s0 * HDIM + lane];
            float v1 = (float)xwh[(size_t)s1 * HDIM + lane];
            float v2 = (float)xwh[(size_t)s2 * HDIM + lane];
            float v3 = (float)xwh[(size_t)s3 * HDIM + lane];
            a0 = fmaf(c0, v0, a0);
            a1 = fmaf(c1, v1, a1);
            a2 = fmaf(c2, v2, a2);
            a3 = fmaf(c3, v3, a3);
        }
        for (; j < cnt; ++j) {
            unsigned u = bkt[j];
            int s = (int)(u >> 15);
            unsigned pe = dc[s];
            a0 = fmaf(rsqrtf(1.0f + (float)(pe & SUM_MASK) * 0x1p-18f) * ((float)(u & 0x7FFFu) * 0x1p-15f),
                      (float)xwh[(size_t)s * HDIM + lane], a0);
        }
        acc = fmaf(dd, (a0 + a1) + (a2 + a3), acc);
    }

    __shared__ float red[256];
    red[tid] = acc;
    __syncthreads();
    if (tid < 64) {
        float s = red[tid] + red[64 + tid] + red[128 + tid] + red[192 + tid];
        atomicAdd(&S[((blockIdx.x * ROWS_PER_BLOCK) / NNEUR) * HDIM + tid], s);  // bt = d/500
    }
}

// ---------------- attention MLP + pooling + FC head (one block) ----------------
__global__ __launch_bounds__(256) void k_final(
    const float* __restrict__ S, const float* __restrict__ W1,
    const float* __restrict__ W2, const float* __restrict__ fcW,
    const float* __restrict__ fcb, float* __restrict__ out)
{
    __shared__ float xt[256];
    __shared__ float a1[128];
    __shared__ float attn[256];
    __shared__ float pooled[512];
    const int tid = threadIdx.x;

    {
        float s = 0.f;
        const float* p = S + tid * 64;
#pragma unroll
        for (int hh = 0; hh < 64; ++hh) s += p[hh];
        xt[tid] = s * (1.0f / 32000.0f);
    }
    __syncthreads();
    if (tid < 128) {
        int b = tid >> 4, i = tid & 15;
        float s = 0.f;
#pragma unroll
        for (int t = 0; t < 32; ++t) s += xt[b * 32 + t] * W1[i * 32 + t];
        a1[tid] = fmaxf(s, 0.f);
    }
    __syncthreads();
    {
        int b = tid >> 5, t = tid & 31;
        float s = 0.f;
#pragma unroll
        for (int i = 0; i < 16; ++i) s += a1[b * 16 + i] * W2[t * 16 + i];
        attn[tid] = 1.0f / (1.0f + __expf(-s));
    }
    __syncthreads();
    for (int o = tid; o < 512; o += 256) {
        int b = o >> 6, h = o & 63;
        float s = 0.f;
#pragma unroll
        for (int t = 0; t < 32; ++t) s += attn[b * 32 + t] * S[(b * 32 + t) * 64 + h];
        pooled[o] = s;
    }
    __syncthreads();
    if (tid < BATCHB * NSTEPS) {
        int b = tid / NSTEPS, st = tid % NSTEPS;
        float acc = fcb[st];
#pragma unroll
        for (int h = 0; h < 64; ++h) acc += pooled[b * 64 + h] * fcW[st * 64 + h];
        out[b * NSTEPS + st] = acc;
    }
}

extern "C" void kernel_launch(void* const* d_in, const int* in_sizes, int n_in,
                              void* d_out, int out_size, void* d_ws, size_t ws_size,
                              hipStream_t stream) {
    const float* x   = (const float*)d_in[0];
    const int*   ei  = (const int*)  d_in[1];
    const float* ea  = (const float*)d_in[2];
    // d_in[3] = batch: unused by the reference computation
    const float* Wih = (const float*)d_in[4];
    const float* Whh = (const float*)d_in[5];
    const float* bih = (const float*)d_in[6];
    const float* bhh = (const float*)d_in[7];
    const float* Wg  = (const float*)d_in[8];
    const float* W1  = (const float*)d_in[9];
    const float* W2  = (const float*)d_in[10];
    const float* fcW = (const float*)d_in[11];
    const float* fcb = (const float*)d_in[12];
    float* out = (float*)d_out;

    // workspace layout (~33.5 MB); dc and S adjacent -> one memset clears both
    char* p = (char*)d_ws;
    unsigned* dc = (unsigned*)p;   p += sizeof(unsigned) * NTOT;                                    // 512000 B
    float* S = (float*)p;          p += sizeof(float) * 256 * HDIM;                                 // 65536 B
    unsigned* se32 = (unsigned*)p; p += sizeof(unsigned) * (size_t)NTOT * SLOTS;                    // 16.38 MB
    _Float16* xwh = (_Float16*)p;  p += sizeof(_Float16) * (size_t)NTOT * HDIM;                     // 16.38 MB

    hipMemsetAsync(dc, 0, sizeof(unsigned) * NTOT + sizeof(float) * 256 * HDIM, stream);
    k_recHist <<<REC_BLOCKS + HIST_BLOCKS, 256, 0, stream>>>(
        x, Wih, Whh, bih, bhh, Wg, xwh, ei, ea, dc, se32);
    k_gather  <<<GATHER_BLOCKS, 256, 0, stream>>>(xwh, dc, se32, S);
    k_final   <<<1, 256, 0, stream>>>(S, W1, W2, fcW, fcb, out);
}